// Round 1
// baseline (2703.711 us; speedup 1.0000x reference)
//
#include <hip/hip_runtime.h>
#include <math.h>

#define TT 64
#define BB 256
#define DD 512
#define HH 512

__device__ __forceinline__ float sigmoidf_(float x){ return 1.f/(1.f+__expf(-x)); }

// ---- quantum pair helpers: amp s = lane + 64*r, r in 0..3 holds bits (7,6) ----
__device__ __forceinline__ void rx_pair(float&ra,float&ia,float&rb,float&ib,float c,float s){
  float r0=ra, i0=ia, r1=rb, i1=ib;
  ra = c*r0 + s*i1;  ia = c*i0 - s*r1;
  rb = s*i0 + c*r1;  ib = c*i1 - s*r0;
}
__device__ __forceinline__ void ry_pair(float&ra,float&ia,float&rb,float&ib,float c,float s){
  float r0=ra, i0=ia, r1=rb, i1=ib;
  ra = c*r0 - s*r1;  ia = c*i0 - s*i1;
  rb = s*r0 + c*r1;  ib = s*i0 + c*i1;
}
__device__ __forceinline__ void rz_amp(float&r,float&i,float c,float sg){
  float r0=r; r = c*r0 + sg*i; i = c*i - sg*r0;
}

// one wave (64 threads) per (batch b, gate g)
__global__ __launch_bounds__(64) void k1_quantum(
    const float* __restrict__ x,   // (T,B,D)
    const float* __restrict__ hx,  // (B,H)
    const float* __restrict__ Wf, const float* __restrict__ Wi,
    const float* __restrict__ Wu, const float* __restrict__ Wo,
    const float* __restrict__ bf, const float* __restrict__ bi,
    const float* __restrict__ bu, const float* __restrict__ bo,
    const float* __restrict__ qpf, const float* __restrict__ qpi,
    const float* __restrict__ qpu, const float* __restrict__ qpo,
    const float* __restrict__ pW1, const float* __restrict__ pb1,
    float* __restrict__ H1, int t)
{
  const int lane = threadIdx.x;
  const int g = blockIdx.x & 3;
  const int b = blockIdx.x >> 2;
  const float* W    = (g==0)?Wf :(g==1)?Wi :(g==2)?Wu :Wo;
  const float* bias = (g==0)?bf :(g==1)?bi :(g==2)?bu :bo;
  const float* qp   = (g==0)?qpf:(g==1)?qpi:(g==2)?qpu:qpo;

  // ---- angles: v = [x_t, hx] @ W + b  (W is (1024,8) row-major) ----
  float acc[8] = {0,0,0,0,0,0,0,0};
  const float* xrow = x + ((size_t)t*BB + b)*DD;
  const float* hrow = hx + (size_t)b*HH;
  #pragma unroll
  for (int it = 0; it < DD/64; ++it){
    int k = lane + it*64;
    float xv = xrow[k];
    const float4* wr = reinterpret_cast<const float4*>(W + (size_t)k*8);
    float4 w0 = wr[0], w1 = wr[1];
    acc[0]+=xv*w0.x; acc[1]+=xv*w0.y; acc[2]+=xv*w0.z; acc[3]+=xv*w0.w;
    acc[4]+=xv*w1.x; acc[5]+=xv*w1.y; acc[6]+=xv*w1.z; acc[7]+=xv*w1.w;
  }
  #pragma unroll
  for (int it = 0; it < HH/64; ++it){
    int k = lane + it*64;
    float hv = hrow[k];
    const float4* wr = reinterpret_cast<const float4*>(W + (size_t)(DD+k)*8);
    float4 w0 = wr[0], w1 = wr[1];
    acc[0]+=hv*w0.x; acc[1]+=hv*w0.y; acc[2]+=hv*w0.z; acc[3]+=hv*w0.w;
    acc[4]+=hv*w1.x; acc[5]+=hv*w1.y; acc[6]+=hv*w1.z; acc[7]+=hv*w1.w;
  }
  float th[8];
  #pragma unroll
  for (int q=0;q<8;q++){
    #pragma unroll
    for (int m=32;m;m>>=1) acc[q] += __shfl_xor(acc[q], m);
    th[q] = acc[q] + bias[q];
  }

  // ---- statevector sim: 256 amps, lane holds s = lane + 64*r ----
  float re[4]={0.f,0.f,0.f,0.f}, im[4]={0.f,0.f,0.f,0.f};
  if (lane==0) re[0]=1.f;

  // RX(x_q, q) for q=0..7
  #pragma unroll
  for (int q=0;q<8;q++){
    float s,c; __sincosf(0.5f*th[q], &s, &c);
    if (q==0){       // stride 128: (r0,r2),(r1,r3)
      rx_pair(re[0],im[0],re[2],im[2],c,s);
      rx_pair(re[1],im[1],re[3],im[3],c,s);
    } else if (q==1){// stride 64: (r0,r1),(r2,r3)
      rx_pair(re[0],im[0],re[1],im[1],c,s);
      rx_pair(re[2],im[2],re[3],im[3],c,s);
    } else {
      const int mask = 1<<(7-q);
      #pragma unroll
      for (int r=0;r<4;r++){
        float rp = __shfl_xor(re[r], mask);
        float ip = __shfl_xor(im[r], mask);
        re[r] = c*re[r] + s*ip;   // role-independent RX update
        im[r] = c*im[r] - s*rp;
      }
    }
  }

  // DEPTH layers: RY,RZ per qubit then CNOT chain
  #pragma unroll
  for (int l=0;l<2;l++){
    #pragma unroll
    for (int q=0;q<8;q++){
      float thy = qp[(l*8+q)*3 + 0];
      float thz = qp[(l*8+q)*3 + 1];
      float s,c; __sincosf(0.5f*thy, &s, &c);
      if (q==0){
        ry_pair(re[0],im[0],re[2],im[2],c,s);
        ry_pair(re[1],im[1],re[3],im[3],c,s);
      } else if (q==1){
        ry_pair(re[0],im[0],re[1],im[1],c,s);
        ry_pair(re[2],im[2],re[3],im[3],c,s);
      } else {
        const int mask = 1<<(7-q);
        float sg = (lane & mask) ? s : -s;
        #pragma unroll
        for (int r=0;r<4;r++){
          float rp = __shfl_xor(re[r], mask);
          float ip = __shfl_xor(im[r], mask);
          re[r] = c*re[r] + sg*rp;
          im[r] = c*im[r] + sg*ip;
        }
      }
      __sincosf(0.5f*thz, &s, &c);
      if (q==0){        // bit7: r0,r1 -> +s ; r2,r3 -> -s
        rz_amp(re[0],im[0],c, s); rz_amp(re[1],im[1],c, s);
        rz_amp(re[2],im[2],c,-s); rz_amp(re[3],im[3],c,-s);
      } else if (q==1){ // bit6: r even +s, r odd -s
        rz_amp(re[0],im[0],c, s); rz_amp(re[2],im[2],c, s);
        rz_amp(re[1],im[1],c,-s); rz_amp(re[3],im[3],c,-s);
      } else {
        const int mask = 1<<(7-q);
        float sg = (lane & mask) ? -s : s;
        #pragma unroll
        for (int r=0;r<4;r++) rz_amp(re[r],im[r],c,sg);
      }
    }
    // CNOT chain ctrl=0..6 (ctrl bit 7-c, target bit 6-c)
    { float tr=re[2]; re[2]=re[3]; re[3]=tr;
      float ti=im[2]; im[2]=im[3]; im[3]=ti; }             // ctrl=0
    re[1]=__shfl_xor(re[1],32); im[1]=__shfl_xor(im[1],32); // ctrl=1 (r=1,3 full swap)
    re[3]=__shfl_xor(re[3],32); im[3]=__shfl_xor(im[3],32);
    #pragma unroll
    for (int cq=2;cq<7;cq++){
      const int cbit = 1<<(7-cq), tbit = 1<<(6-cq);
      const bool sw = (lane & cbit) != 0;
      #pragma unroll
      for (int r=0;r<4;r++){
        float rp = __shfl_xor(re[r], tbit);
        float ip = __shfl_xor(im[r], tbit);
        re[r] = sw ? rp : re[r];
        im[r] = sw ? ip : im[r];
      }
    }
  }

  // ---- measure Z ----
  float p0=re[0]*re[0]+im[0]*im[0];
  float p1=re[1]*re[1]+im[1]*im[1];
  float p2=re[2]*re[2]+im[2]*im[2];
  float p3=re[3]*re[3]+im[3]*im[3];
  float tot = p0+p1+p2+p3;
  float z[8];
  z[0] = (p0+p1)-(p2+p3);  // bit7
  z[1] = (p0+p2)-(p1+p3);  // bit6
  #pragma unroll
  for (int q=2;q<8;q++)
    z[q] = (lane & (1<<(7-q))) ? -tot : tot;
  #pragma unroll
  for (int q=0;q<8;q++){
    #pragma unroll
    for (int m=32;m;m>>=1) z[q] += __shfl_xor(z[q], m);
  }

  // ---- H1 row = relu(z @ pW1 + pb1), row index m = b*4+g ----
  float* h1row = H1 + ((size_t)b*4 + g)*HH;
  #pragma unroll
  for (int it=0; it<HH/64; ++it){
    int j = lane + it*64;
    float a = pb1[j];
    #pragma unroll
    for (int q=0;q<8;q++) a += z[q]*pW1[q*HH+j];
    h1row[j] = fmaxf(a, 0.f);
  }
}

// GEMM H1(1024x512) @ pW2(512x512) + fused LSTM. M row = b*4+g.
__global__ __launch_bounds__(256) void k2_gemm_lstm(
    const float* __restrict__ H1, const float* __restrict__ pW2,
    const float* __restrict__ pb2, float* __restrict__ cx,
    float* __restrict__ hx, float* __restrict__ out, int t)
{
  __shared__ float As[16][68];  // [kk][m_local]
  __shared__ float Bs[16][68];  // [kk][n_local]
  const int tid = threadIdx.x;
  const int tx = tid & 15, ty = tid >> 4;
  const int n0 = blockIdx.x * 64;
  const int m0 = blockIdx.y * 64;   // 16 batches x 4 gates
  float acc[4][4] = {{0,0,0,0},{0,0,0,0},{0,0,0,0},{0,0,0,0}};

  for (int k0 = 0; k0 < 512; k0 += 16){
    __syncthreads();
    {
      const int kk = tid & 15, ml = tid >> 4;      // A: transpose-store
      #pragma unroll
      for (int r=0;r<4;r++)
        As[kk][ml + 16*r] = H1[(size_t)(m0 + ml + 16*r)*512 + k0 + kk];
      const int nl = tid & 63, kb = tid >> 6;      // B: straight store
      #pragma unroll
      for (int r=0;r<4;r++)
        Bs[kb + 4*r][nl] = pW2[(size_t)(k0 + kb + 4*r)*512 + n0 + nl];
    }
    __syncthreads();
    #pragma unroll
    for (int kk=0;kk<16;kk++){
      float4 av = *reinterpret_cast<const float4*>(&As[kk][ty*4]);
      float4 bv = *reinterpret_cast<const float4*>(&Bs[kk][tx*4]);
      float a[4] = {av.x,av.y,av.z,av.w};
      float bv4[4] = {bv.x,bv.y,bv.z,bv.w};
      #pragma unroll
      for (int i=0;i<4;i++)
        #pragma unroll
        for (int j=0;j<4;j++)
          acc[i][j] += a[i]*bv4[j];
    }
  }

  // epilogue: this thread holds gates f,i,u,o (rows ty*4+0..3) for batch b
  const int b = (m0 >> 2) + ty;
  #pragma unroll
  for (int j=0;j<4;j++){
    const int n = n0 + tx*4 + j;
    const float bias = pb2[n];
    float f  = sigmoidf_(acc[0][j] + bias);
    float ii = sigmoidf_(acc[1][j] + bias);
    float u  = tanhf    (acc[2][j] + bias);
    float o  = sigmoidf_(acc[3][j] + bias);
    float c2 = f * cx[(size_t)b*HH + n] + ii * u;
    float h2 = o * tanhf(c2);
    cx[(size_t)b*HH + n] = c2;
    hx[(size_t)b*HH + n] = h2;
    out[((size_t)t*BB + b)*HH + n] = h2;
  }
}

extern "C" void kernel_launch(void* const* d_in, const int* in_sizes, int n_in,
                              void* d_out, int out_size, void* d_ws, size_t ws_size,
                              hipStream_t stream)
{
  const float* x   = (const float*)d_in[0];
  const float* qpf = (const float*)d_in[1];
  const float* qpi = (const float*)d_in[2];
  const float* qpu = (const float*)d_in[3];
  const float* qpo = (const float*)d_in[4];
  const float* Wf  = (const float*)d_in[5];
  const float* bf  = (const float*)d_in[6];
  const float* Wi  = (const float*)d_in[7];
  const float* bi  = (const float*)d_in[8];
  const float* Wu  = (const float*)d_in[9];
  const float* bu  = (const float*)d_in[10];
  const float* Wo  = (const float*)d_in[11];
  const float* bo  = (const float*)d_in[12];
  const float* pW1 = (const float*)d_in[13];
  const float* pb1 = (const float*)d_in[14];
  const float* pW2 = (const float*)d_in[15];
  const float* pb2 = (const float*)d_in[16];

  float* out = (float*)d_out;
  float* hx = (float*)d_ws;                  // B*H
  float* cx = hx + (size_t)BB*HH;            // B*H
  float* H1 = cx + (size_t)BB*HH;            // 1024*512

  hipMemsetAsync(hx, 0, (size_t)2*BB*HH*sizeof(float), stream);

  for (int t=0; t<TT; ++t){
    k1_quantum<<<dim3(BB*4), dim3(64), 0, stream>>>(
        x, hx, Wf,Wi,Wu,Wo, bf,bi,bu,bo, qpf,qpi,qpu,qpo, pW1,pb1, H1, t);
    k2_gemm_lstm<<<dim3(8,16), dim3(256), 0, stream>>>(
        H1, pW2, pb2, cx, hx, out, t);
  }

  hipMemcpyAsync(out + (size_t)TT*BB*HH, hx,
                 (size_t)BB*HH*sizeof(float), hipMemcpyDeviceToDevice, stream);
  hipMemcpyAsync(out + (size_t)TT*BB*HH + (size_t)BB*HH, cx,
                 (size_t)BB*HH*sizeof(float), hipMemcpyDeviceToDevice, stream);
}

// Round 2
// 1517.944 us; speedup vs baseline: 1.7812x; 1.7812x over previous
//
#include <hip/hip_runtime.h>
#include <hip/hip_bf16.h>
#include <math.h>

#define TT 64
#define BB 256
#define DD 512
#define HH 512

typedef __attribute__((ext_vector_type(8))) short bf16x8;
typedef __attribute__((ext_vector_type(4))) float f32x4;

__device__ __forceinline__ float sigmoidf_(float x){ return 1.f/(1.f+__expf(-x)); }

// ---- quantum pair helpers: amp s = lane + 64*r, r in 0..3 holds bits (7,6) ----
__device__ __forceinline__ void rx_pair(float&ra,float&ia,float&rb,float&ib,float c,float s){
  float r0=ra, i0=ia, r1=rb, i1=ib;
  ra = c*r0 + s*i1;  ia = c*i0 - s*r1;
  rb = s*i0 + c*r1;  ib = c*i1 - s*r0;
}
__device__ __forceinline__ void ry_pair(float&ra,float&ia,float&rb,float&ib,float c,float s){
  float r0=ra, i0=ia, r1=rb, i1=ib;
  ra = c*r0 - s*r1;  ia = c*i0 - s*i1;
  rb = s*r0 + c*r1;  ib = s*i0 + c*i1;
}
__device__ __forceinline__ void rz_amp(float&r,float&i,float c,float sg){
  float r0=r; r = c*r0 + sg*i; i = c*i - sg*r0;
}

// ---- one-time: XW[t,b,g,q] = x[t,b,:] @ W_g[:512,q] + bias_g[q] ----
__global__ __launch_bounds__(256) void k0_xw(
    const float* __restrict__ x,
    const float* __restrict__ Wf, const float* __restrict__ Wi,
    const float* __restrict__ Wu, const float* __restrict__ Wo,
    const float* __restrict__ bfv, const float* __restrict__ biv,
    const float* __restrict__ buv, const float* __restrict__ bov,
    float* __restrict__ XW)
{
  const int gid = blockIdx.x*256 + threadIdx.x;   // over TT*BB*32
  const int col = gid & 31;
  const int tb  = gid >> 5;
  const int g = col >> 3, q = col & 7;
  const float* W    = (g==0)?Wf :(g==1)?Wi :(g==2)?Wu :Wo;
  const float* bias = (g==0)?bfv:(g==1)?biv:(g==2)?buv:bov;
  const float* xrow = x + (size_t)tb*DD;
  float a0=0.f, a1=0.f;
  #pragma unroll 8
  for (int k=0;k<DD;k+=2){
    a0 += xrow[k]   * W[(size_t)k*8 + q];
    a1 += xrow[k+1] * W[(size_t)(k+1)*8 + q];
  }
  XW[gid] = a0 + a1 + bias[q];
}

// ---- one-time: W2t[n][k] = bf16(pW2[k][n]) ----
__global__ __launch_bounds__(64) void k0_w2t(
    const float* __restrict__ pW2, __hip_bfloat16* __restrict__ W2t)
{
  const int n = blockIdx.x;
  const int lane = threadIdx.x;
  #pragma unroll
  for (int i=0;i<HH/64;i++){
    int k = lane + i*64;
    W2t[(size_t)n*HH + k] = __float2bfloat16(pW2[(size_t)k*HH + n]);
  }
}

// one wave (64 threads) per (batch b, gate g): hx-part of angles + quantum + H1 row
__global__ __launch_bounds__(64) void k1_quantum(
    const float* __restrict__ XW,  // (T,B,4,8) incl. bias + x-part
    const float* __restrict__ hx,  // (B,H)
    const float* __restrict__ Wf, const float* __restrict__ Wi,
    const float* __restrict__ Wu, const float* __restrict__ Wo,
    const float* __restrict__ qpf, const float* __restrict__ qpi,
    const float* __restrict__ qpu, const float* __restrict__ qpo,
    const float* __restrict__ pW1, const float* __restrict__ pb1,
    __hip_bfloat16* __restrict__ H1, int t)
{
  const int lane = threadIdx.x;
  const int g = blockIdx.x & 3;
  const int b = blockIdx.x >> 2;
  const float* W  = (g==0)?Wf :(g==1)?Wi :(g==2)?Wu :Wo;
  const float* qp = (g==0)?qpf:(g==1)?qpi:(g==2)?qpu:qpo;

  // ---- angles: th = XW_row + hx @ W[512:1024] ----
  float acc[8] = {0,0,0,0,0,0,0,0};
  const float* hrow = hx + (size_t)b*HH;
  #pragma unroll
  for (int it = 0; it < HH/64; ++it){
    int k = lane + it*64;
    float hv = hrow[k];
    const float4* wr = reinterpret_cast<const float4*>(W + (size_t)(DD+k)*8);
    float4 w0 = wr[0], w1 = wr[1];
    acc[0]+=hv*w0.x; acc[1]+=hv*w0.y; acc[2]+=hv*w0.z; acc[3]+=hv*w0.w;
    acc[4]+=hv*w1.x; acc[5]+=hv*w1.y; acc[6]+=hv*w1.z; acc[7]+=hv*w1.w;
  }
  const float* xwrow = XW + (((size_t)t*BB + b)*4 + g)*8;
  float th[8];
  #pragma unroll
  for (int q=0;q<8;q++){
    #pragma unroll
    for (int m=32;m;m>>=1) acc[q] += __shfl_xor(acc[q], m);
    th[q] = acc[q] + xwrow[q];
  }

  // ---- statevector sim: 256 amps, lane holds s = lane + 64*r ----
  float re[4]={0.f,0.f,0.f,0.f}, im[4]={0.f,0.f,0.f,0.f};
  if (lane==0) re[0]=1.f;

  #pragma unroll
  for (int q=0;q<8;q++){
    float s,c; __sincosf(0.5f*th[q], &s, &c);
    if (q==0){
      rx_pair(re[0],im[0],re[2],im[2],c,s);
      rx_pair(re[1],im[1],re[3],im[3],c,s);
    } else if (q==1){
      rx_pair(re[0],im[0],re[1],im[1],c,s);
      rx_pair(re[2],im[2],re[3],im[3],c,s);
    } else {
      const int mask = 1<<(7-q);
      #pragma unroll
      for (int r=0;r<4;r++){
        float rp = __shfl_xor(re[r], mask);
        float ip = __shfl_xor(im[r], mask);
        re[r] = c*re[r] + s*ip;
        im[r] = c*im[r] - s*rp;
      }
    }
  }

  #pragma unroll
  for (int l=0;l<2;l++){
    #pragma unroll
    for (int q=0;q<8;q++){
      float thy = qp[(l*8+q)*3 + 0];
      float thz = qp[(l*8+q)*3 + 1];
      float s,c; __sincosf(0.5f*thy, &s, &c);
      if (q==0){
        ry_pair(re[0],im[0],re[2],im[2],c,s);
        ry_pair(re[1],im[1],re[3],im[3],c,s);
      } else if (q==1){
        ry_pair(re[0],im[0],re[1],im[1],c,s);
        ry_pair(re[2],im[2],re[3],im[3],c,s);
      } else {
        const int mask = 1<<(7-q);
        float sg = (lane & mask) ? s : -s;
        #pragma unroll
        for (int r=0;r<4;r++){
          float rp = __shfl_xor(re[r], mask);
          float ip = __shfl_xor(im[r], mask);
          re[r] = c*re[r] + sg*rp;
          im[r] = c*im[r] + sg*ip;
        }
      }
      __sincosf(0.5f*thz, &s, &c);
      if (q==0){
        rz_amp(re[0],im[0],c, s); rz_amp(re[1],im[1],c, s);
        rz_amp(re[2],im[2],c,-s); rz_amp(re[3],im[3],c,-s);
      } else if (q==1){
        rz_amp(re[0],im[0],c, s); rz_amp(re[2],im[2],c, s);
        rz_amp(re[1],im[1],c,-s); rz_amp(re[3],im[3],c,-s);
      } else {
        const int mask = 1<<(7-q);
        float sg = (lane & mask) ? -s : s;
        #pragma unroll
        for (int r=0;r<4;r++) rz_amp(re[r],im[r],c,sg);
      }
    }
    { float tr=re[2]; re[2]=re[3]; re[3]=tr;
      float ti=im[2]; im[2]=im[3]; im[3]=ti; }
    re[1]=__shfl_xor(re[1],32); im[1]=__shfl_xor(im[1],32);
    re[3]=__shfl_xor(re[3],32); im[3]=__shfl_xor(im[3],32);
    #pragma unroll
    for (int cq=2;cq<7;cq++){
      const int cbit = 1<<(7-cq), tbit = 1<<(6-cq);
      const bool sw = (lane & cbit) != 0;
      #pragma unroll
      for (int r=0;r<4;r++){
        float rp = __shfl_xor(re[r], tbit);
        float ip = __shfl_xor(im[r], tbit);
        re[r] = sw ? rp : re[r];
        im[r] = sw ? ip : im[r];
      }
    }
  }

  // ---- measure Z ----
  float p0=re[0]*re[0]+im[0]*im[0];
  float p1=re[1]*re[1]+im[1]*im[1];
  float p2=re[2]*re[2]+im[2]*im[2];
  float p3=re[3]*re[3]+im[3]*im[3];
  float tot = p0+p1+p2+p3;
  float z[8];
  z[0] = (p0+p1)-(p2+p3);
  z[1] = (p0+p2)-(p1+p3);
  #pragma unroll
  for (int q=2;q<8;q++)
    z[q] = (lane & (1<<(7-q))) ? -tot : tot;
  #pragma unroll
  for (int q=0;q<8;q++){
    #pragma unroll
    for (int m=32;m;m>>=1) z[q] += __shfl_xor(z[q], m);
  }

  // ---- H1 row (bf16) = relu(z @ pW1 + pb1), row m = b*4+g ----
  __hip_bfloat16* h1row = H1 + ((size_t)b*4 + g)*HH;
  #pragma unroll
  for (int it=0; it<HH/64; ++it){
    int j = lane + it*64;
    float a = pb1[j];
    #pragma unroll
    for (int q=0;q<8;q++) a += z[q]*pW1[q*HH+j];
    h1row[j] = __float2bfloat16(fmaxf(a, 0.f));
  }
}

// MFMA GEMM: G = H1(1024x512,bf16) @ W2t^T + fused LSTM. M row = b*4+g.
__global__ __launch_bounds__(256) void k2_mfma_lstm(
    const __hip_bfloat16* __restrict__ H1, const __hip_bfloat16* __restrict__ W2t,
    const float* __restrict__ pb2, float* __restrict__ cx,
    float* __restrict__ hx, float* __restrict__ out, int t)
{
  __shared__ short As[64][64];  // [m][k], 16B chunks XOR-swizzled by (m&7)
  __shared__ short Bs[64][64];  // [n][k], 16B chunks XOR-swizzled by (n&7)
  const int tid = threadIdx.x;
  const int lane = tid & 63;
  const int w = tid >> 6;
  const int wr = w >> 1, wc = w & 1;     // wave's 32x32 quadrant
  const int n0 = blockIdx.x * 64;
  const int m0 = blockIdx.y * 64;

  f32x4 acc[2][2];
  #pragma unroll
  for (int i=0;i<2;i++)
    #pragma unroll
    for (int j=0;j<2;j++) acc[i][j] = (f32x4){0.f,0.f,0.f,0.f};

  const int srow  = tid >> 3;   // 0..31
  const int schk  = tid & 7;    // 16B chunk within 128B row

  for (int k0 = 0; k0 < HH; k0 += 64){
    __syncthreads();
    #pragma unroll
    for (int iss=0; iss<2; ++iss){
      const int r = srow + 32*iss;
      const uint4 va = *reinterpret_cast<const uint4*>(H1  + (size_t)(m0 + r)*HH + k0 + schk*8);
      *reinterpret_cast<uint4*>(&As[r][(schk ^ (r&7))*8]) = va;
      const uint4 vb = *reinterpret_cast<const uint4*>(W2t + (size_t)(n0 + r)*HH + k0 + schk*8);
      *reinterpret_cast<uint4*>(&Bs[r][(schk ^ (r&7))*8]) = vb;
    }
    __syncthreads();
    #pragma unroll
    for (int kk=0; kk<2; ++kk){
      bf16x8 af[2], bg[2];
      #pragma unroll
      for (int fm=0; fm<2; ++fm){
        const int row = wr*32 + fm*16 + (lane&15);
        const int ks  = (kk*32 + (lane>>4)*8) ^ ((row&7)<<3);
        af[fm] = *reinterpret_cast<const bf16x8*>(&As[row][ks]);
      }
      #pragma unroll
      for (int fn=0; fn<2; ++fn){
        const int nr = wc*32 + fn*16 + (lane&15);
        const int ks = (kk*32 + (lane>>4)*8) ^ ((nr&7)<<3);
        bg[fn] = *reinterpret_cast<const bf16x8*>(&Bs[nr][ks]);
      }
      #pragma unroll
      for (int fm=0; fm<2; ++fm)
        #pragma unroll
        for (int fn=0; fn<2; ++fn)
          acc[fm][fn] = __builtin_amdgcn_mfma_f32_16x16x32_bf16(af[fm], bg[fn], acc[fm][fn], 0,0,0);
    }
  }

  // epilogue: C reg r -> row (lane>>4)*4 + r = b*4 + gate  (f,i,u,o)
  const int a4 = (lane>>4)*4;
  #pragma unroll
  for (int fm=0; fm<2; ++fm){
    const int mbase = m0 + wr*32 + fm*16 + a4;   // multiple of 4
    const int b = mbase >> 2;
    #pragma unroll
    for (int fn=0; fn<2; ++fn){
      const int n = n0 + wc*32 + fn*16 + (lane&15);
      const float bias = pb2[n];
      const float fga = sigmoidf_(acc[fm][fn][0] + bias);
      const float iga = sigmoidf_(acc[fm][fn][1] + bias);
      const float uga = tanhf   (acc[fm][fn][2] + bias);
      const float oga = sigmoidf_(acc[fm][fn][3] + bias);
      const float c2 = fga * cx[(size_t)b*HH + n] + iga * uga;
      const float h2 = oga * tanhf(c2);
      cx[(size_t)b*HH + n] = c2;
      hx[(size_t)b*HH + n] = h2;
      out[((size_t)t*BB + b)*HH + n] = h2;
    }
  }
}

extern "C" void kernel_launch(void* const* d_in, const int* in_sizes, int n_in,
                              void* d_out, int out_size, void* d_ws, size_t ws_size,
                              hipStream_t stream)
{
  const float* x   = (const float*)d_in[0];
  const float* qpf = (const float*)d_in[1];
  const float* qpi = (const float*)d_in[2];
  const float* qpu = (const float*)d_in[3];
  const float* qpo = (const float*)d_in[4];
  const float* Wf  = (const float*)d_in[5];
  const float* bf  = (const float*)d_in[6];
  const float* Wi  = (const float*)d_in[7];
  const float* bi  = (const float*)d_in[8];
  const float* Wu  = (const float*)d_in[9];
  const float* bu  = (const float*)d_in[10];
  const float* Wo  = (const float*)d_in[11];
  const float* bo  = (const float*)d_in[12];
  const float* pW1 = (const float*)d_in[13];
  const float* pb1 = (const float*)d_in[14];
  const float* pW2 = (const float*)d_in[15];
  const float* pb2 = (const float*)d_in[16];

  float* out = (float*)d_out;
  float* hx = (float*)d_ws;                                   // B*H f32
  float* cx = hx + (size_t)BB*HH;                             // B*H f32
  float* XW = cx + (size_t)BB*HH;                             // T*B*32 f32
  __hip_bfloat16* H1  = (__hip_bfloat16*)(XW + (size_t)TT*BB*32);  // 1024*512 bf16
  __hip_bfloat16* W2t = H1 + (size_t)(BB*4)*HH;                    // 512*512 bf16

  hipMemsetAsync(hx, 0, (size_t)2*BB*HH*sizeof(float), stream);

  k0_xw<<<dim3((TT*BB*32)/256), dim3(256), 0, stream>>>(
      x, Wf,Wi,Wu,Wo, bf,bi,bu,bo, XW);
  k0_w2t<<<dim3(HH), dim3(64), 0, stream>>>(pW2, W2t);

  for (int t=0; t<TT; ++t){
    k1_quantum<<<dim3(BB*4), dim3(64), 0, stream>>>(
        XW, hx, Wf,Wi,Wu,Wo, qpf,qpi,qpu,qpo, pW1,pb1, H1, t);
    k2_mfma_lstm<<<dim3(8,16), dim3(256), 0, stream>>>(
        H1, W2t, pb2, cx, hx, out, t);
  }

  hipMemcpyAsync(out + (size_t)TT*BB*HH, hx,
                 (size_t)BB*HH*sizeof(float), hipMemcpyDeviceToDevice, stream);
  hipMemcpyAsync(out + (size_t)TT*BB*HH + (size_t)BB*HH, cx,
                 (size_t)BB*HH*sizeof(float), hipMemcpyDeviceToDevice, stream);
}